// Round 1
// baseline (1170.197 us; speedup 1.0000x reference)
//
#include <hip/hip_runtime.h>
#include <hip/hip_bf16.h>

// Hierarchical softmax loss:
//   G=256 groups, C=256 children/group, D = G + G*C = 65792 logits per row, B=4096 rows.
//   loss = mean_b [ -log_softmax(row[0:256])[group]
//                   -log_softmax(row[256+group*256 : 256+(group+1)*256])[child] ]
// One 256-thread block per row; thread i owns slot i of each 256-wide softmax.

#define HSM_G 256
#define HSM_C 256
#define HSM_D (HSM_G + HSM_G * HSM_C)   // 65792
#define HSM_B 4096

__global__ __launch_bounds__(256) void hsm_loss_kernel(
    const float* __restrict__ pred,   // [B, D] fp32
    const int*   __restrict__ tgt,    // [B] int32 (harness converts int64 -> int32)
    float* __restrict__ out)          // [1] fp32, pre-zeroed
{
    const int row = blockIdx.x;
    const int tid = threadIdx.x;          // 0..255
    const int t     = tgt[row];
    const int group = t >> 8;             // t / C
    const int child = t & 255;            // t % C

    const float* rowp = pred + (size_t)row * HSM_D;

    __shared__ float sred[4];             // per-wave partials (4 waves of 64)
    __shared__ float sx[2];               // target-slot logit per phase

    float ce_sum = 0.0f;

#pragma unroll
    for (int phase = 0; phase < 2; ++phase) {
        const int base = (phase == 0) ? 0 : (HSM_G + group * HSM_C);
        const int idx  = (phase == 0) ? group : child;

        const float x = rowp[base + tid]; // coalesced 1 KB per block
        if (tid == idx) sx[phase] = x;

        // ---- block max ----
        float m = x;
        for (int off = 32; off > 0; off >>= 1)
            m = fmaxf(m, __shfl_down(m, off));     // wave64 shuffle
        if ((tid & 63) == 0) sred[tid >> 6] = m;
        __syncthreads();
        m = fmaxf(fmaxf(sred[0], sred[1]), fmaxf(sred[2], sred[3]));
        __syncthreads();                           // sred reused below

        // ---- block sum of exp(x - m) ----
        float s = expf(x - m);
        for (int off = 32; off > 0; off >>= 1)
            s += __shfl_down(s, off);
        if ((tid & 63) == 0) sred[tid >> 6] = s;
        __syncthreads();
        s = sred[0] + sred[1] + sred[2] + sred[3];
        __syncthreads();                           // sred reused next phase

        // ce = -(x_target - m - log(sum))
        ce_sum += -(sx[phase] - m - logf(s));
    }

    if (tid == 0)
        atomicAdd(out, ce_sum * (1.0f / (float)HSM_B));
}

extern "C" void kernel_launch(void* const* d_in, const int* in_sizes, int n_in,
                              void* d_out, int out_size, void* d_ws, size_t ws_size,
                              hipStream_t stream) {
    const float* pred = (const float*)d_in[0];
    const int*   tgt  = (const int*)d_in[1];
    float* out = (float*)d_out;

    // d_out is re-poisoned to 0xAA before every timed launch; zero it on-stream
    // (hipMemsetAsync is graph-capture safe), then accumulate via atomicAdd.
    hipMemsetAsync(out, 0, sizeof(float), stream);

    hsm_loss_kernel<<<HSM_B, 256, 0, stream>>>(pred, tgt, out);
}

// Round 2
// 1113.094 us; speedup vs baseline: 1.0513x; 1.0513x over previous
//
#include <hip/hip_runtime.h>
#include <hip/hip_bf16.h>

// Hierarchical softmax loss, two-stage (no global atomics):
//   G=256 groups, C=256 children/group, D = 65792 logits/row, B=4096 rows.
//   loss = mean_b [ -log_softmax(row[0:256])[group]
//                   -log_softmax(row[256+group*256 : ...])[child] ]
//
// Stage 1: one wave (64 lanes) per row, float4 loads (64*16B = 256 floats per
//          softmax) -> pure in-wave butterfly reductions, no __syncthreads in
//          the per-phase path. 4 rows/block, 1024 blocks. One partial/block
//          into d_ws (fully overwritten every call, so 0xAA poison is fine).
// Stage 2: single block reduces the 1024 partials, writes out[0] directly
//          (store, not accumulate -> no memset of d_out needed).

#define HSM_G 256
#define HSM_C 256
#define HSM_D (HSM_G + HSM_G * HSM_C)   // 65792
#define HSM_B 4096
#define ROWS_PER_BLOCK 4                 // 4 waves of 64
#define N_BLOCKS (HSM_B / ROWS_PER_BLOCK)  // 1024

__global__ __launch_bounds__(256) void hsm_partial_kernel(
    const float* __restrict__ pred,    // [B, D] fp32
    const int*   __restrict__ tgt,     // [B] int32
    float*       __restrict__ partial) // [N_BLOCKS] fp32 (in d_ws)
{
    const int wave = threadIdx.x >> 6;       // 0..3
    const int lane = threadIdx.x & 63;       // 0..63
    const int row  = blockIdx.x * ROWS_PER_BLOCK + wave;

    const int t     = tgt[row];
    const int group = t >> 8;                // t / C
    const int child = t & 255;               // t % C
    const float* rowp = pred + (size_t)row * HSM_D;

    float ce = 0.0f;

#pragma unroll
    for (int phase = 0; phase < 2; ++phase) {
        const int base = (phase == 0) ? 0 : (HSM_G + (group << 8));
        const int idx  = (phase == 0) ? group : child;   // wave-uniform

        // 64 lanes x float4 = the full 256-wide softmax, coalesced 1 KB
        const float4 v = *(const float4*)(rowp + base + (lane << 2));

        // target logit: owner lane = idx>>2, component = idx&3 (wave-uniform)
        const int comp = idx & 3;
        const float cand = (comp == 0) ? v.x : (comp == 1) ? v.y
                         : (comp == 2) ? v.z : v.w;
        const float xt = __shfl(cand, idx >> 2);

        // wave max
        float m = fmaxf(fmaxf(v.x, v.y), fmaxf(v.z, v.w));
#pragma unroll
        for (int off = 32; off; off >>= 1) m = fmaxf(m, __shfl_xor(m, off));

        // wave sum of exp(x - m)
        float s = expf(v.x - m) + expf(v.y - m) + expf(v.z - m) + expf(v.w - m);
#pragma unroll
        for (int off = 32; off; off >>= 1) s += __shfl_xor(s, off);

        ce += (m + logf(s)) - xt;            // -(xt - m - log s)
    }

    __shared__ float sred[ROWS_PER_BLOCK];
    if (lane == 0) sred[wave] = ce;
    __syncthreads();
    if (threadIdx.x == 0)
        partial[blockIdx.x] = sred[0] + sred[1] + sred[2] + sred[3];
}

__global__ __launch_bounds__(256) void hsm_final_kernel(
    const float* __restrict__ partial,  // [N_BLOCKS]
    float*       __restrict__ out)      // [1]
{
    const int tid = threadIdx.x;
    const float4 v = ((const float4*)partial)[tid];   // 256 * 4 = 1024
    float s = v.x + v.y + v.z + v.w;
#pragma unroll
    for (int off = 32; off; off >>= 1) s += __shfl_xor(s, off);

    __shared__ float sred[4];
    if ((tid & 63) == 0) sred[tid >> 6] = s;
    __syncthreads();
    if (tid == 0)
        out[0] = (sred[0] + sred[1] + sred[2] + sred[3]) * (1.0f / (float)HSM_B);
}

extern "C" void kernel_launch(void* const* d_in, const int* in_sizes, int n_in,
                              void* d_out, int out_size, void* d_ws, size_t ws_size,
                              hipStream_t stream) {
    const float* pred = (const float*)d_in[0];
    const int*   tgt  = (const int*)d_in[1];
    float* out     = (float*)d_out;
    float* partial = (float*)d_ws;   // 1024 floats = 4 KB scratch

    hsm_partial_kernel<<<N_BLOCKS, 256, 0, stream>>>(pred, tgt, partial);
    hsm_final_kernel<<<1, 256, 0, stream>>>(partial, out);
}